// Round 8
// baseline (916.790 us; speedup 1.0000x reference)
//
#include <hip/hip_runtime.h>

#define NW   8192
#define NT   49
#define CDIM 192
#define NH   6
#define HD   32

typedef __attribute__((ext_vector_type(4))) float f32x4;
typedef __attribute__((ext_vector_type(8))) short bf16x8;

__device__ __forceinline__ unsigned short f2b(float f) {
  union { float f; unsigned u; } v; v.f = f;
  unsigned r = v.u + 0x7fffu + ((v.u >> 16) & 1u);   // round-to-nearest-even
  return (unsigned short)(r >> 16);
}
__device__ __forceinline__ float b2f(unsigned short u) {
  union { unsigned u; float f; } v; v.u = ((unsigned)u) << 16; return v.f;
}

// LDS plan (76.1 KB, 2 blocks/CU). Field ORDER matters: padded-row fragment reads
// (token rows 49..63) of xb overflow into Ob (zeroed at start, finite bf16 after),
// and Ob pad-row reads in proj overflow into qg (finite bf16). All overflow targets
// hold finite bf16 at every read point -> no NaN/Inf contamination of valid rows.
struct __align__(16) Smem {
  unsigned short xb[NT][200];   // x (bf16), stride 200 ushorts (400B)
  unsigned short Ob[NT][200];   // attention output accum (bf16); zeroed at start
  unsigned short qg[64][72];    // q for head pair, group-local cols [tok][2*32], stride 144B
  unsigned short kg[64][72];    // k for head pair
  unsigned short vT[64][72];    // v transposed [feat_local][tok]
  unsigned short P [64][72];    // exp(S) (bf16); rows wave-exclusive (it == wave)
};

// ---- prep: weight transpose+cvt (scale folded into q cols), bias gather ----
__global__ void prep_w(const float* __restrict__ qkv_w, const float* __restrict__ qkv_b,
                       const float* __restrict__ proj_w,
                       unsigned short* __restrict__ wT, unsigned short* __restrict__ projT,
                       float* __restrict__ qb) {
  int idx = blockIdx.x * 256 + threadIdx.x;
  const float scale = 0.17677669529663687f;  // 32^-0.5
  if (idx < 576 * 192) {                     // wT[n][c] = qkv_w[c][n] (*scale for q cols)
    int n = idx / 192, c = idx % 192;
    float v = qkv_w[c * 576 + n];
    if (n < 192) v *= scale;
    wT[idx] = f2b(v);
  } else if (idx < 576 * 192 + 192 * 192) {  // projT[n][c] = proj_w[c][n]
    int j = idx - 576 * 192;
    int n = j / 192, c = j % 192;
    projT[j] = f2b(proj_w[c * 192 + n]);
  } else if (idx < 576 * 192 + 192 * 192 + 576) {
    int n = idx - (576 * 192 + 192 * 192);
    float v = qkv_b[n];
    if (n < 192) v *= scale;
    qb[n] = v;
  }
}

// biasF[h][it][jt][lane][reg] bf16, C-fragment order; -1e30 outside 49x49 = fused mask
__global__ void prep_bias(const float* __restrict__ table, const int* __restrict__ rel,
                          unsigned short* __restrict__ biasF) {
  int idx = blockIdx.x * 256 + threadIdx.x;
  if (idx >= NH * 4 * 4 * 64 * 4) return;
  int reg = idx & 3, lane = (idx >> 2) & 63, jt = (idx >> 8) & 3,
      it = (idx >> 10) & 3, h = idx >> 12;
  int i = it * 16 + (lane >> 4) * 4 + reg;
  int j = jt * 16 + (lane & 15);
  float v = -1e30f;
  if (i < NT && j < NT) v = table[rel[i * NT + j] * NH + h];
  biasF[idx] = f2b(v);
}

// ---- fused window attention: 1 block = 1 window, heads processed in 3 pairs ----
__global__ __launch_bounds__(256, 2) void fused_winattn(
    const float* __restrict__ x, const float* __restrict__ projb,
    const unsigned short* __restrict__ wT, const unsigned short* __restrict__ projT,
    const float* __restrict__ qb, const unsigned short* __restrict__ biasF,
    float* __restrict__ out) {
  __shared__ Smem sm;
  const int tid  = threadIdx.x;
  const int lane = tid & 63;
  const int wave = tid >> 6;
  const int l15  = lane & 15;
  const int quad = lane >> 4;
  const int win  = blockIdx.x;

  // zero ONLY Ob (19.6 KB): it is the overflow target for xb pad-row reads and must
  // be finite before group-0 QKV. (Was: full 59.7 KB zero.)
  {
    int4 z = {0, 0, 0, 0};
    int4* p = (int4*)&sm.Ob[0][0];
    for (int i = tid; i < (int)(sizeof(sm.Ob) / 16); i += 256) p[i] = z;
  }
  // stage x -> bf16 LDS (coalesced float4)
  const float* xw = x + (size_t)win * (NT * CDIM);
  for (int idx = tid; idx < NT * CDIM / 4; idx += 256) {
    int row = idx / 48, c4 = idx % 48;
    float4 v = ((const float4*)xw)[idx];
    ushort4 pk; pk.x = f2b(v.x); pk.y = f2b(v.y); pk.z = f2b(v.z); pk.w = f2b(v.w);
    *(ushort4*)&sm.xb[row][c4 * 4] = pk;
  }
  __syncthreads();

  const int it = wave;   // each wave owns i-tile == wave throughout attention

  for (int g = 0; g < 3; ++g) {            // head pair g: heads 2g, 2g+1
    // ---- QKV GEMM for this pair: 12 feature tiles, wave w = feature tile w of
    //      each section (sec 0=q swapped, 1=k swapped, 2=v normal).
    //      Weight fragments hoisted: each wT row read ONCE per block (was 4x).
    #pragma unroll
    for (int sec = 0; sec < 3; ++sec) {
      const int f0 = sec * CDIM + g * 64 + wave * 16;     // global wT row base
      const unsigned short* wrow = wT + (size_t)(f0 + l15) * CDIM + quad * 8;
      bf16x8 wf[6];
      #pragma unroll
      for (int k2 = 0; k2 < 6; ++k2) wf[k2] = *(const bf16x8*)(wrow + k2 * 32);

      if (sec < 2) {
        // swapped: A=wT,B=x -> C[feat][tok]; contiguous 4-feature stores per token
        float4 bq = *(const float4*)(qb + f0 + quad * 4);
        unsigned short* dstb = (sec == 0) ? &sm.qg[0][0] : &sm.kg[0][0];
        #pragma unroll
        for (int tt = 0; tt < 4; ++tt) {
          const unsigned short* xrow = &sm.xb[0][0] + (size_t)(tt * 16 + l15) * 200 + quad * 8;
          f32x4 acc = {0.f, 0.f, 0.f, 0.f};
          #pragma unroll
          for (int k2 = 0; k2 < 6; ++k2)
            acc = __builtin_amdgcn_mfma_f32_16x16x32_bf16(
                wf[k2], *(const bf16x8*)(xrow + k2 * 32), acc, 0, 0, 0);
          acc[0] += bq.x; acc[1] += bq.y; acc[2] += bq.z; acc[3] += bq.w;
          int tok = tt * 16 + l15;
          ushort4 pk;
          if (tok < NT) {                  // zero pad tokens: keeps S pad rows bounded
            pk.x = f2b(acc[0]); pk.y = f2b(acc[1]); pk.z = f2b(acc[2]); pk.w = f2b(acc[3]);
          } else { pk.x = pk.y = pk.z = pk.w = 0; }
          *(ushort4*)(dstb + (size_t)tok * 72 + wave * 16 + quad * 4) = pk;
        }
      } else {
        // normal: A=x,B=wT -> C[tok][feat]; contiguous 4-token stores per feature
        float bv = qb[f0 + l15];
        #pragma unroll
        for (int tt = 0; tt < 4; ++tt) {
          const unsigned short* xrow = &sm.xb[0][0] + (size_t)(tt * 16 + l15) * 200 + quad * 8;
          f32x4 acc = {0.f, 0.f, 0.f, 0.f};
          #pragma unroll
          for (int k2 = 0; k2 < 6; ++k2)
            acc = __builtin_amdgcn_mfma_f32_16x16x32_bf16(
                *(const bf16x8*)(xrow + k2 * 32), wf[k2], acc, 0, 0, 0);
          int j0 = tt * 16 + quad * 4;
          // pad tokens j>=49: P is exactly 0 there (bias -1e30 -> exp==0.f), so any
          // finite value is safe; zero them anyway to mirror known-good behavior
          ushort4 pk;
          pk.x = (j0 + 0 < NT) ? f2b(acc[0] + bv) : (unsigned short)0;
          pk.y = (j0 + 1 < NT) ? f2b(acc[1] + bv) : (unsigned short)0;
          pk.z = (j0 + 2 < NT) ? f2b(acc[2] + bv) : (unsigned short)0;
          pk.w = (j0 + 3 < NT) ? f2b(acc[3] + bv) : (unsigned short)0;
          *(ushort4*)(&sm.vT[0][0] + (size_t)(wave * 16 + l15) * 72 + j0) = pk;
        }
      }
    }
    __syncthreads();

    // ---- attention for both heads of the pair: ZERO intra-phase barriers.
    //      P rows / Ob rows / sinv are wave-exclusive (it == wave); q/k/vT read-only.
    #pragma unroll
    for (int hl = 0; hl < 2; ++hl) {
      const int h = g * 2 + hl;
      bf16x8 aq = *(const bf16x8*)(&sm.qg[0][0] + (size_t)(it * 16 + l15) * 72 + hl * 32 + quad * 8);
      f32x4 s[4];
      #pragma unroll
      for (int jt = 0; jt < 4; ++jt) {
        bf16x8 bk = *(const bf16x8*)(&sm.kg[0][0] + (size_t)(jt * 16 + l15) * 72 + hl * 32 + quad * 8);
        f32x4 z = {0.f, 0.f, 0.f, 0.f};
        s[jt] = __builtin_amdgcn_mfma_f32_16x16x32_bf16(aq, bk, z, 0, 0, 0);
        ushort4 bb = *(const ushort4*)(biasF + ((((h * 4 + it) * 4 + jt) * 64) + lane) * 4);
        s[jt][0] += b2f(bb.x); s[jt][1] += b2f(bb.y);
        s[jt][2] += b2f(bb.z); s[jt][3] += b2f(bb.w);
      }
      // softmax WITHOUT max pass: S ~ N(0,1) (+/-0.1 bias), overflow needs S>88 --
      // mathematically identical ratios, pad cols give exp(-1e30)==0.f exactly.
      float e[4][4], sinv[4];
      #pragma unroll
      for (int r = 0; r < 4; ++r) {
        float e0 = __expf(s[0][r]), e1 = __expf(s[1][r]);
        float e2 = __expf(s[2][r]), e3 = __expf(s[3][r]);
        e[0][r] = e0; e[1][r] = e1; e[2][r] = e2; e[3][r] = e3;
        float sum = (e0 + e1) + (e2 + e3);
        #pragma unroll
        for (int off = 1; off < 16; off <<= 1) sum += __shfl_xor(sum, off, 16);
        sinv[r] = __builtin_amdgcn_rcpf(sum);   // kept in regs; bf16-rounded anyway
      }
      #pragma unroll
      for (int jt = 0; jt < 4; ++jt)
        #pragma unroll
        for (int r = 0; r < 4; ++r)
          sm.P[it * 16 + quad * 4 + r][jt * 16 + l15] = f2b(e[jt][r]);
      // O = P.V (unnormalized), scale by sinv at store
      bf16x8 ap0 = *(const bf16x8*)(&sm.P[0][0] + (size_t)(it * 16 + l15) * 72 + quad * 8);
      bf16x8 ap1 = *(const bf16x8*)(&sm.P[0][0] + (size_t)(it * 16 + l15) * 72 + 32 + quad * 8);
      #pragma unroll
      for (int dt = 0; dt < 2; ++dt) {
        const unsigned short* vrow = &sm.vT[0][0] + (size_t)(hl * 32 + dt * 16 + l15) * 72;
        bf16x8 bv0 = *(const bf16x8*)(vrow + quad * 8);
        bf16x8 bv1 = *(const bf16x8*)(vrow + 32 + quad * 8);
        f32x4 o = {0.f, 0.f, 0.f, 0.f};
        o = __builtin_amdgcn_mfma_f32_16x16x32_bf16(ap0, bv0, o, 0, 0, 0);
        o = __builtin_amdgcn_mfma_f32_16x16x32_bf16(ap1, bv1, o, 0, 0, 0);
        #pragma unroll
        for (int r = 0; r < 4; ++r) {
          int i = it * 16 + quad * 4 + r;
          if (i < NT)
            sm.Ob[i][h * HD + dt * 16 + l15] = f2b(o[r] * sinv[r]);
        }
      }
    }
    __syncthreads();   // protects qg/kg/vT overwrite by next pair; last one guards proj
  }

  // ---- proj: out = Ob @ projT^T + b ; wave handles n-tiles {wave, wave+4, wave+8}
  for (int nn = 0; nn < 3; ++nn) {
    int nt = wave + nn * 4;
    int n0 = nt * 16;
    const unsigned short* wrow = projT + (size_t)(n0 + l15) * CDIM + quad * 8;
    bf16x8 bw[6];
    #pragma unroll
    for (int k = 0; k < 6; ++k) bw[k] = *(const bf16x8*)(wrow + k * 32);
    float pb = projb[n0 + l15];
    #pragma unroll
    for (int mt = 0; mt < 4; ++mt) {
      f32x4 acc = {0.f, 0.f, 0.f, 0.f};
      #pragma unroll
      for (int k = 0; k < 6; ++k) {
        bf16x8 ao = *(const bf16x8*)(&sm.Ob[0][0] + (size_t)(mt * 16 + l15) * 200 + k * 32 + quad * 8);
        acc = __builtin_amdgcn_mfma_f32_16x16x32_bf16(ao, bw[k], acc, 0, 0, 0);
      }
      int i0 = mt * 16 + quad * 4;
      #pragma unroll
      for (int r = 0; r < 4; ++r) {
        int i = i0 + r;
        if (i < NT)
          out[((size_t)win * NT + i) * CDIM + n0 + l15] = acc[r] + pb;
      }
    }
  }
}

extern "C" void kernel_launch(void* const* d_in, const int* in_sizes, int n_in,
                              void* d_out, int out_size, void* d_ws, size_t ws_size,
                              hipStream_t stream) {
  const float* x      = (const float*)d_in[0];
  const float* qkv_w  = (const float*)d_in[1];
  const float* qkv_b  = (const float*)d_in[2];
  const float* proj_w = (const float*)d_in[3];
  const float* proj_b = (const float*)d_in[4];
  const float* table  = (const float*)d_in[5];
  const int*   rel    = (const int*)d_in[6];
  float* out = (float*)d_out;

  char* ws = (char*)d_ws;                      // 346,368 B used
  unsigned short* wT    = (unsigned short*)(ws);                    // 576*192 bf16
  unsigned short* projT = (unsigned short*)(ws + 221184);           // 192*192 bf16
  float*          qb    = (float*)(ws + 221184 + 73728);            // 576 f32
  unsigned short* biasF = (unsigned short*)(ws + 221184 + 73728 + 2304); // 24576 bf16

  prep_w<<<579, 256, 0, stream>>>(qkv_w, qkv_b, proj_w, wT, projT, qb);
  prep_bias<<<96, 256, 0, stream>>>(table, rel, biasF);
  fused_winattn<<<NW, 256, 0, stream>>>(x, proj_b, wT, projT, qb, biasF, out);
}